// Round 1
// baseline (374.375 us; speedup 1.0000x reference)
//
#include <hip/hip_runtime.h>
#include <math.h>

// RoPE "rotation matrix * x" — ELEMENTWISE product with a 2x2-block-diagonal R.
// out[b,i,j] == 0 except j in {i&~1, (i&~1)+1}.
//
// Strategy change vs previous version: the 256 MiB of zeros is now written by
// hipMemsetAsync (rocclr fillBuffer path, measured 6.4 TB/s in this harness),
// and the kernel only patches the 2 non-zero entries per row:
//   B*D = 32768 rows  ->  512 KiB of float2 stores, 512 KiB of reads.
//
// D=2048, B=16, BASE=10000, m is a runtime int input.

constexpr int D = 2048;
constexpr int B = 16;

__global__ __launch_bounds__(256) void rope_patch_kernel(
        const float* __restrict__ x, const int* __restrict__ m_ptr,
        float* __restrict__ out) {
    const int t = blockIdx.x * blockDim.x + threadIdx.x;   // 0 .. B*D-1, one per row
    const int i  = t & (D - 1);                            // row within the (D,D) matrix
    const int c0 = i & ~1;                                 // column of the 2x2 block
    const int p  = i >> 1;                                 // pair index, 0..1023

    const int m = *m_ptr;
    // ang = m / BASE^(2p/D); double precision (only 32K threads total, cost ~µs)
    const double ang = (double)m * exp((-2.0 * (double)p / (double)D) * log(10000.0));
    const float c = (float)cos(ang);
    const float s = (float)sin(ang);

    // flat element offset of (b, i, c0): (b*D + i)*D + c0 == t*D + c0
    const long long base = (long long)t * D + c0;
    const float2 xv = *(const float2*)(x + base);

    float2 v;
    if (i & 1) {            // odd row (i=2p+1): [ s, c ]
        v.x = s * xv.x;
        v.y = c * xv.y;
    } else {                // even row (i=2p): [ c, -s ]
        v.x = c * xv.x;
        v.y = -s * xv.y;
    }
    *(float2*)(out + base) = v;
}

extern "C" void kernel_launch(void* const* d_in, const int* in_sizes, int n_in,
                              void* d_out, int out_size, void* d_ws, size_t ws_size,
                              hipStream_t stream) {
    const float* x     = (const float*)d_in[0];
    const int*   m_ptr = (const int*)d_in[1];
    float*       out   = (float*)d_out;

    // 1) Zero the whole output via the rocclr fill path (~42 µs @ 6.4 TB/s).
    //    hipMemsetAsync is stream-ordered and graph-capturable.
    hipMemsetAsync(d_out, 0, (size_t)B * D * D * sizeof(float), stream);

    // 2) Patch the 2 non-zero entries of each of the B*D rows.
    const int block = 256;
    const int grid  = (B * D) / block;    // 128 blocks
    rope_patch_kernel<<<grid, block, 0, stream>>>(x, m_ptr, out);
}